// Round 1
// baseline (8249.645 us; speedup 1.0000x reference)
//
#include <hip/hip_runtime.h>

#define N_USERS_C 100000
#define N_ITEMS_C 40000
#define NTOT_C    140000
#define DIM_C     64

// ---------------------------------------------------------------------------
// Scatter-atomic SpMM: out[rows[e], :] += vals[e] * x[cols[e], :]
// 16 threads per edge, each handling 4 consecutive dims via float4 gather.
// ---------------------------------------------------------------------------
__global__ __launch_bounds__(256) void spmm_atomic(
    const int* __restrict__ rows, const int* __restrict__ cols,
    const float* __restrict__ vals, const float* __restrict__ x,
    float* __restrict__ out, int nnz) {
    int gid = blockIdx.x * blockDim.x + threadIdx.x;
    int e = gid >> 4;
    int q = gid & 15;
    if (e >= nnz) return;
    int r = rows[e];
    int c = cols[e];
    float v = vals[e];
    const float4 xv = *(const float4*)(x + (size_t)c * DIM_C + q * 4);
    float* o = out + (size_t)r * DIM_C + q * 4;
    atomicAdd(o + 0, v * xv.x);
    atomicAdd(o + 1, v * xv.y);
    atomicAdd(o + 2, v * xv.z);
    atomicAdd(o + 3, v * xv.w);
}

// acc[i] += b[i], float4-vectorized. n4 = count of float4 elements.
__global__ __launch_bounds__(256) void acc_add(
    float* __restrict__ acc, const float* __restrict__ b, int n4) {
    int gid = blockIdx.x * blockDim.x + threadIdx.x;
    if (gid >= n4) return;
    float4 a = ((float4*)acc)[gid];
    float4 bb = ((const float4*)b)[gid];
    a.x += bb.x; a.y += bb.y; a.z += bb.z; a.w += bb.w;
    ((float4*)acc)[gid] = a;
}

// Epilogue: one wave (64 lanes) per row.
//   user rows:  out_u[r] = acc[r]*0.25 + uu[r]/max(||uu[r]||, eps)
//   item rows:  out_i[r] = acc[r]*0.25 + ii[r-NU]/max(||ii[r-NU]||, eps)
// acc lives in-place in d_out[0 : NTOT*64].
__global__ __launch_bounds__(256) void finalize_rows(
    float* __restrict__ acc, const float* __restrict__ ii_fin,
    const float* __restrict__ uu_fin) {
    int gid = blockIdx.x * blockDim.x + threadIdx.x;
    int row = gid >> 6;
    int d = gid & 63;
    if (row >= NTOT_C) return;
    const float* src = (row < N_USERS_C)
        ? (uu_fin + (size_t)row * DIM_C)
        : (ii_fin + (size_t)(row - N_USERS_C) * DIM_C);
    float v = src[d];
    float ss = v * v;
    #pragma unroll
    for (int off = 32; off > 0; off >>= 1) ss += __shfl_xor(ss, off, 64);
    float norm = sqrtf(ss);
    float denom = fmaxf(norm, 1e-12f);
    size_t idx = (size_t)row * DIM_C + d;
    acc[idx] = acc[idx] * 0.25f + v / denom;
}

static inline void launch_spmm(const int* rows, const int* cols, const float* vals,
                               const float* x, float* out, int nnz, hipStream_t s) {
    int threads = nnz * 16;
    int blocks = (threads + 255) / 256;
    spmm_atomic<<<blocks, 256, 0, s>>>(rows, cols, vals, x, out, nnz);
}

extern "C" void kernel_launch(void* const* d_in, const int* in_sizes, int n_in,
                              void* d_out, int out_size, void* d_ws, size_t ws_size,
                              hipStream_t stream) {
    const float* user_ui = (const float*)d_in[0];
    const float* item_ui = (const float*)d_in[1];
    const float* uu_emb  = (const float*)d_in[2];
    const float* ii_emb  = (const float*)d_in[3];
    const float* ui_vals = (const float*)d_in[4];
    const float* ii_vals = (const float*)d_in[5];
    const float* uu_vals = (const float*)d_in[6];
    const int* ui_rows = (const int*)d_in[7];
    const int* ui_cols = (const int*)d_in[8];
    const int* ii_rows = (const int*)d_in[9];
    const int* ii_cols = (const int*)d_in[10];
    const int* uu_rows = (const int*)d_in[11];
    const int* uu_cols = (const int*)d_in[12];
    const int nnz_ui = in_sizes[4];
    const int nnz_ii = in_sizes[5];
    const int nnz_uu = in_sizes[6];

    float* out    = (float*)d_out;
    float* out_u  = out;                                  // [100000, 64] (acc user part)
    float* out_i  = out + (size_t)N_USERS_C * DIM_C;      // [40000, 64]  (acc item part)
    float* out_ii = out + (size_t)NTOT_C * DIM_C;         // [40000, 64]  final ii
    float* out_uu = out_ii + (size_t)N_ITEMS_C * DIM_C;   // [100000, 64] final uu

    float* bufA = (float*)d_ws;                        // NTOT*64 floats (35.84 MB)
    float* bufB = bufA + (size_t)NTOT_C * DIM_C;       // NTOT*64 floats

    const size_t bytesN    = (size_t)NTOT_C * DIM_C * sizeof(float);
    const size_t bytesU    = (size_t)N_USERS_C * DIM_C * sizeof(float);
    const size_t bytesI    = (size_t)N_ITEMS_C * DIM_C * sizeof(float);

    // ---- ii chain: ii_emb -> bufA -> out_ii (2 layers) ----
    hipMemsetAsync(bufA, 0, bytesI, stream);
    launch_spmm(ii_rows, ii_cols, ii_vals, ii_emb, bufA, nnz_ii, stream);
    hipMemsetAsync(out_ii, 0, bytesI, stream);
    launch_spmm(ii_rows, ii_cols, ii_vals, bufA, out_ii, nnz_ii, stream);

    // ---- uu chain: uu_emb -> bufB -> out_uu (2 layers) ----
    hipMemsetAsync(bufB, 0, bytesU, stream);
    launch_spmm(uu_rows, uu_cols, uu_vals, uu_emb, bufB, nnz_uu, stream);
    hipMemsetAsync(out_uu, 0, bytesU, stream);
    launch_spmm(uu_rows, uu_cols, uu_vals, bufB, out_uu, nnz_uu, stream);

    // ---- ui chain: acc (in d_out[0:NTOT*64]) = ego0; 3 layers ----
    hipMemcpyAsync(out_u, user_ui, bytesU, hipMemcpyDeviceToDevice, stream);
    hipMemcpyAsync(out_i, item_ui, bytesI, hipMemcpyDeviceToDevice, stream);

    const int n4 = (int)((size_t)NTOT_C * DIM_C / 4);
    const int add_blocks = (n4 + 255) / 256;

    // layer 1: ego1 = spmm(ego0=out[0:NTOT]), acc += ego1
    hipMemsetAsync(bufA, 0, bytesN, stream);
    launch_spmm(ui_rows, ui_cols, ui_vals, out, bufA, nnz_ui, stream);
    acc_add<<<add_blocks, 256, 0, stream>>>(out, bufA, n4);

    // layer 2: ego2 = spmm(ego1=bufA), acc += ego2
    hipMemsetAsync(bufB, 0, bytesN, stream);
    launch_spmm(ui_rows, ui_cols, ui_vals, bufA, bufB, nnz_ui, stream);
    acc_add<<<add_blocks, 256, 0, stream>>>(out, bufB, n4);

    // layer 3: ego3 = spmm(ego2=bufB), acc += ego3
    hipMemsetAsync(bufA, 0, bytesN, stream);
    launch_spmm(ui_rows, ui_cols, ui_vals, bufB, bufA, nnz_ui, stream);
    acc_add<<<add_blocks, 256, 0, stream>>>(out, bufA, n4);

    // ---- epilogue: acc/4 + l2_normalize(ii|uu) ----
    {
        int threads = NTOT_C * 64;
        int blocks = (threads + 255) / 256;
        finalize_rows<<<blocks, 256, 0, stream>>>(out, out_ii, out_uu);
    }
}

// Round 2
// 1102.335 us; speedup vs baseline: 7.4838x; 7.4838x over previous
//
#include <hip/hip_runtime.h>

#define N_USERS_C 100000
#define N_ITEMS_C 40000
#define NTOT_C    140000
#define DIM_C     64
#define SCAN_B    256

// ---------------------------------------------------------------------------
// CSR build: histogram -> chunked inclusive scan -> partials scan -> finalize
// ---------------------------------------------------------------------------
__global__ __launch_bounds__(256) void hist_rows(
    const int* __restrict__ rows, int* __restrict__ counts, int nnz) {
    int e = blockIdx.x * blockDim.x + threadIdx.x;
    if (e < nnz) atomicAdd(&counts[rows[e]], 1);
}

// Phase A: per-256-chunk inclusive scan of counts -> tmp; chunk totals -> partials
__global__ __launch_bounds__(SCAN_B) void scan_chunks(
    const int* __restrict__ counts, int* __restrict__ tmp,
    int* __restrict__ partials, int n) {
    __shared__ int s[SCAN_B];
    int i = blockIdx.x * SCAN_B + threadIdx.x;
    int v = (i < n) ? counts[i] : 0;
    s[threadIdx.x] = v;
    __syncthreads();
    #pragma unroll
    for (int off = 1; off < SCAN_B; off <<= 1) {
        int t = (threadIdx.x >= off) ? s[threadIdx.x - off] : 0;
        __syncthreads();
        s[threadIdx.x] += t;
        __syncthreads();
    }
    if (i < n) tmp[i] = s[threadIdx.x];
    if (threadIdx.x == SCAN_B - 1) partials[blockIdx.x] = s[SCAN_B - 1];
}

// Phase B: single-block exclusive scan of partials in place (C <= 1024)
__global__ __launch_bounds__(SCAN_B) void scan_partials(int* __restrict__ partials, int C) {
    __shared__ int s[SCAN_B];
    __shared__ int carry;
    if (threadIdx.x == 0) carry = 0;
    __syncthreads();
    for (int base = 0; base < C; base += SCAN_B) {
        int carryv = carry;
        int i = base + threadIdx.x;
        int v = (i < C) ? partials[i] : 0;
        s[threadIdx.x] = v;
        __syncthreads();
        #pragma unroll
        for (int off = 1; off < SCAN_B; off <<= 1) {
            int t = (threadIdx.x >= off) ? s[threadIdx.x - off] : 0;
            __syncthreads();
            s[threadIdx.x] += t;
            __syncthreads();
        }
        int total = s[SCAN_B - 1];
        if (i < C) partials[i] = s[threadIdx.x] - v + carryv;  // exclusive
        __syncthreads();
        if (threadIdx.x == 0) carry = carryv + total;
        __syncthreads();
    }
}

// Phase C: row_ptr[i+1] = partials[chunk] + tmp[i]; cursor[i] = row start
__global__ __launch_bounds__(SCAN_B) void finalize_rowptr(
    const int* __restrict__ counts, const int* __restrict__ tmp,
    const int* __restrict__ partials, int* __restrict__ rowptr,
    int* __restrict__ cursor, int n) {
    int i = blockIdx.x * SCAN_B + threadIdx.x;
    if (i >= n) return;
    int incl = partials[blockIdx.x] + tmp[i];
    rowptr[i + 1] = incl;
    cursor[i] = incl - counts[i];
    if (i == 0) rowptr[0] = 0;
}

__global__ __launch_bounds__(256) void scatter_edges(
    const int* __restrict__ rows, const int* __restrict__ cols,
    const float* __restrict__ vals, int* __restrict__ cursor,
    int* __restrict__ scol, float* __restrict__ sval, int nnz) {
    int e = blockIdx.x * blockDim.x + threadIdx.x;
    if (e >= nnz) return;
    int r = rows[e];
    int pos = atomicAdd(&cursor[r], 1);
    scol[pos] = cols[e];
    sval[pos] = vals[e];
}

// ---------------------------------------------------------------------------
// Gather SpMM (CSR): one wave per row, lane = dim. Coalesced 256B gathers.
//   out[row] = sum_j val_j * x[col_j]      (out nullable)
//   acc[row] += sum                         (acc nullable)
// ---------------------------------------------------------------------------
__global__ __launch_bounds__(256) void spmm_csr(
    const int* __restrict__ rowptr, const int* __restrict__ scol,
    const float* __restrict__ sval, const float* __restrict__ x,
    float* __restrict__ out, float* __restrict__ acc, int n_rows) {
    int w = (blockIdx.x * blockDim.x + threadIdx.x) >> 6;
    int lane = threadIdx.x & 63;
    if (w >= n_rows) return;
    int j = rowptr[w];
    int e = rowptr[w + 1];
    float s0 = 0.f, s1 = 0.f, s2 = 0.f, s3 = 0.f;
    for (; j + 3 < e; j += 4) {
        int c0 = scol[j], c1 = scol[j + 1], c2 = scol[j + 2], c3 = scol[j + 3];
        float v0 = sval[j], v1 = sval[j + 1], v2 = sval[j + 2], v3 = sval[j + 3];
        s0 += v0 * x[(size_t)c0 * DIM_C + lane];
        s1 += v1 * x[(size_t)c1 * DIM_C + lane];
        s2 += v2 * x[(size_t)c2 * DIM_C + lane];
        s3 += v3 * x[(size_t)c3 * DIM_C + lane];
    }
    for (; j < e; ++j) s0 += sval[j] * x[(size_t)scol[j] * DIM_C + lane];
    float s = (s0 + s1) + (s2 + s3);
    size_t idx = (size_t)w * DIM_C + lane;
    if (out) out[idx] = s;
    if (acc) acc[idx] += s;
}

// Epilogue: one wave per row; acc = acc*0.25 + l2norm(src)
__global__ __launch_bounds__(256) void finalize_rows(
    float* __restrict__ acc, const float* __restrict__ ii_fin,
    const float* __restrict__ uu_fin) {
    int gid = blockIdx.x * blockDim.x + threadIdx.x;
    int row = gid >> 6;
    int d = gid & 63;
    if (row >= NTOT_C) return;
    const float* src = (row < N_USERS_C)
        ? (uu_fin + (size_t)row * DIM_C)
        : (ii_fin + (size_t)(row - N_USERS_C) * DIM_C);
    float v = src[d];
    float ss = v * v;
    #pragma unroll
    for (int off = 32; off > 0; off >>= 1) ss += __shfl_xor(ss, off, 64);
    float denom = fmaxf(sqrtf(ss), 1e-12f);
    size_t idx = (size_t)row * DIM_C + d;
    acc[idx] = acc[idx] * 0.25f + v / denom;
}

// ---------------------------------------------------------------------------

struct CsrWs {
    int* scol;      // [max_nnz]
    float* sval;    // [max_nnz]
    int* counts;    // [NTOT]
    int* tmp;       // [NTOT]
    int* rowptr;    // [NTOT+1]
    int* cursor;    // [NTOT]
    int* partials;  // [1024]
};

static inline void build_csr(const int* rows, const int* cols, const float* vals,
                             int nnz, int n_rows, const CsrWs& W, hipStream_t s) {
    hipMemsetAsync(W.counts, 0, (size_t)n_rows * sizeof(int), s);
    int eb = (nnz + 255) / 256;
    hist_rows<<<eb, 256, 0, s>>>(rows, W.counts, nnz);
    int C = (n_rows + SCAN_B - 1) / SCAN_B;
    scan_chunks<<<C, SCAN_B, 0, s>>>(W.counts, W.tmp, W.partials, n_rows);
    scan_partials<<<1, SCAN_B, 0, s>>>(W.partials, C);
    finalize_rowptr<<<C, SCAN_B, 0, s>>>(W.counts, W.tmp, W.partials,
                                         W.rowptr, W.cursor, n_rows);
    scatter_edges<<<eb, 256, 0, s>>>(rows, cols, vals, W.cursor, W.scol, W.sval, nnz);
}

static inline void run_spmm(const CsrWs& W, const float* x, float* out, float* acc,
                            int n_rows, hipStream_t s) {
    int blocks = (n_rows * 64 + 255) / 256;
    spmm_csr<<<blocks, 256, 0, s>>>(W.rowptr, W.scol, W.sval, x, out, acc, n_rows);
}

extern "C" void kernel_launch(void* const* d_in, const int* in_sizes, int n_in,
                              void* d_out, int out_size, void* d_ws, size_t ws_size,
                              hipStream_t stream) {
    const float* user_ui = (const float*)d_in[0];
    const float* item_ui = (const float*)d_in[1];
    const float* uu_emb  = (const float*)d_in[2];
    const float* ii_emb  = (const float*)d_in[3];
    const float* ui_vals = (const float*)d_in[4];
    const float* ii_vals = (const float*)d_in[5];
    const float* uu_vals = (const float*)d_in[6];
    const int* ui_rows = (const int*)d_in[7];
    const int* ui_cols = (const int*)d_in[8];
    const int* ii_rows = (const int*)d_in[9];
    const int* ii_cols = (const int*)d_in[10];
    const int* uu_rows = (const int*)d_in[11];
    const int* uu_cols = (const int*)d_in[12];
    const int nnz_ui = in_sizes[4];
    const int nnz_ii = in_sizes[5];
    const int nnz_uu = in_sizes[6];
    const int max_nnz = nnz_ui > nnz_uu ? (nnz_ui > nnz_ii ? nnz_ui : nnz_ii)
                                        : (nnz_uu > nnz_ii ? nnz_uu : nnz_ii);

    float* out    = (float*)d_out;
    float* acc    = out;                                  // [140000, 64]
    float* out_ii = out + (size_t)NTOT_C * DIM_C;         // [40000, 64]
    float* out_uu = out_ii + (size_t)N_ITEMS_C * DIM_C;   // [100000, 64]
    float* out_tail = out_ii;                             // contiguous NTOT*64 region

    // Workspace carve-up
    char* p = (char*)d_ws;
    float* bufA = (float*)p;               p += (size_t)NTOT_C * DIM_C * sizeof(float);
    CsrWs W;
    W.scol     = (int*)p;                  p += (size_t)max_nnz * sizeof(int);
    W.sval     = (float*)p;                p += (size_t)max_nnz * sizeof(float);
    W.counts   = (int*)p;                  p += (size_t)NTOT_C * sizeof(int);
    W.tmp      = (int*)p;                  p += (size_t)NTOT_C * sizeof(int);
    W.rowptr   = (int*)p;                  p += (size_t)(NTOT_C + 1) * sizeof(int);
    W.cursor   = (int*)p;                  p += (size_t)NTOT_C * sizeof(int);
    W.partials = (int*)p;                  p += 1024 * sizeof(int);

    const size_t bytesU = (size_t)N_USERS_C * DIM_C * sizeof(float);
    const size_t bytesI = (size_t)N_ITEMS_C * DIM_C * sizeof(float);

    // ==== ui chain (3 layers, acc in d_out head) ====
    build_csr(ui_rows, ui_cols, ui_vals, nnz_ui, NTOT_C, W, stream);
    // ego0 -> acc and bufA
    hipMemcpyAsync(acc, user_ui, bytesU, hipMemcpyDeviceToDevice, stream);
    hipMemcpyAsync(acc + (size_t)N_USERS_C * DIM_C, item_ui, bytesI,
                   hipMemcpyDeviceToDevice, stream);
    hipMemcpyAsync(bufA, user_ui, bytesU, hipMemcpyDeviceToDevice, stream);
    hipMemcpyAsync(bufA + (size_t)N_USERS_C * DIM_C, item_ui, bytesI,
                   hipMemcpyDeviceToDevice, stream);
    // L1: ego1 = S*ego0(bufA) -> out_tail, acc += ego1
    run_spmm(W, bufA, out_tail, acc, NTOT_C, stream);
    // L2: ego2 = S*ego1(out_tail) -> bufA, acc += ego2
    run_spmm(W, out_tail, bufA, acc, NTOT_C, stream);
    // L3: ego3 = S*ego2(bufA), only acc += ego3 (no store)
    run_spmm(W, bufA, nullptr, acc, NTOT_C, stream);

    // ==== ii chain (2 layers) ====
    build_csr(ii_rows, ii_cols, ii_vals, nnz_ii, N_ITEMS_C, W, stream);
    run_spmm(W, ii_emb, bufA, nullptr, N_ITEMS_C, stream);
    run_spmm(W, bufA, out_ii, nullptr, N_ITEMS_C, stream);

    // ==== uu chain (2 layers) ====
    build_csr(uu_rows, uu_cols, uu_vals, nnz_uu, N_USERS_C, W, stream);
    run_spmm(W, uu_emb, bufA, nullptr, N_USERS_C, stream);
    run_spmm(W, bufA, out_uu, nullptr, N_USERS_C, stream);

    // ==== epilogue: acc = acc/4 + l2norm(ii|uu) ====
    {
        int threads = NTOT_C * 64;
        int blocks = (threads + 255) / 256;
        finalize_rows<<<blocks, 256, 0, stream>>>(acc, out_ii, out_uu);
    }
}